// Round 2
// baseline (231.697 us; speedup 1.0000x reference)
//
#include <hip/hip_runtime.h>

constexpr int kB  = 16;
constexpr int kLM = 1024;
constexpr int kLX = 1024;
constexpr int kD  = 768;

using short8 = __attribute__((ext_vector_type(8))) short;
using f32x4  = __attribute__((ext_vector_type(4))) float;

__device__ __forceinline__ unsigned short f2bf(float f) {
    unsigned u = __float_as_uint(f);
    u = (u + 0x7FFF + ((u >> 16) & 1)) >> 16;   // RNE
    return (unsigned short)u;
}
__device__ __forceinline__ float bf2f(unsigned short h) {
    return __uint_as_float(((unsigned)h) << 16);
}

// async 16B global->LDS copy; dst must be wave-uniform base + lane*16.
__device__ __forceinline__ void gl_lds16(const unsigned short* g, unsigned short* l) {
    auto gp = (const __attribute__((address_space(1))) unsigned int*)g;
    auto lp = (__attribute__((address_space(3))) unsigned int*)l;
    __builtin_amdgcn_global_load_lds(gp, lp, 16, 0, 0);
}

// cvt 8 fp32 -> one 16B bf16 chunk
__device__ __forceinline__ void writeChunk(unsigned short* dst, float4 lo, float4 hi) {
    union { short8 v; unsigned short u[8]; } o;
    o.u[0] = f2bf(lo.x); o.u[1] = f2bf(lo.y); o.u[2] = f2bf(lo.z); o.u[3] = f2bf(lo.w);
    o.u[4] = f2bf(hi.x); o.u[5] = f2bf(hi.y); o.u[6] = f2bf(hi.z); o.u[7] = f2bf(hi.w);
    *(short8*)dst = o.v;
}

// inverse XOR swizzle: LDS chunk index -> global (row, kseg) element offset
__device__ __forceinline__ size_t chunk_off(int c, int K) {
    int sr = c >> 3, s = c & 7;
    int tt = s ^ (sr & 7);
    int r  = sr * 2 + (tt >> 2);
    int q  = tt & 3;
    return (size_t)r * K + q * 8;
}

// ---------------------------------------------------------------------------
// Common 128x128 NT bf16 MFMA GEMM core. BK=32, 256 thr (2x2 waves), 4x4
// MFMA/wave. C[i][j] = sum_k A[i,k] B[j,k]. XOR-swizzled 16B-chunk LDS.
// 2 LDS buffers (32 KB total -> 5 blocks/CU), depth-2 issue, counted
// vmcnt(4): stage(t+2) issued after BAR2(t) into the buffer just consumed;
// at top of iter t we wait vmcnt(4) (own tile-t loads done; tile t+1 stays
// in flight across both barriers), then BAR1 makes all waves' tile-t loads
// visible. Cm != nullptr: also write the mirrored (transposed) tile.
// ---------------------------------------------------------------------------
__device__ __forceinline__ void gemm_core(
    const unsigned short* __restrict__ Ab, const unsigned short* __restrict__ Bb,
    unsigned short* __restrict__ Cb, unsigned short* __restrict__ Cm,
    int N, int K, unsigned short* As0, unsigned short* Bs0) {
    const int t    = threadIdx.x;
    const int wave = t >> 6, lane = t & 63;
    const int wr = (wave >> 1) * 64, wc = (wave & 1) * 64;
    const int quad = lane >> 4, l15 = lane & 15;

    const int c0 = t, c1 = t + 256;
    const size_t off0 = chunk_off(c0, K);
    const size_t off1 = chunk_off(c1, K);

    const int sfr  = ((l15 & 1) * 4 + quad) ^ ((l15 >> 1) & 7);
    const int aOff = wr * 32 + (l15 >> 1) * 64 + sfr * 8;
    const int bOff = wc * 32 + (l15 >> 1) * 64 + sfr * 8;

    f32x4 acc[4][4];
    const f32x4 z = {0.f, 0.f, 0.f, 0.f};
#pragma unroll
    for (int i = 0; i < 4; ++i)
#pragma unroll
        for (int j = 0; j < 4; ++j) acc[i][j] = z;

    const int T = K >> 5;

    auto stage = [&](int kt, int sel) {
        const size_t k = (size_t)kt << 5;
        unsigned short* Ad = As0 + sel * 4096;
        unsigned short* Bd = Bs0 + sel * 4096;
        gl_lds16(Ab + off0 + k, Ad + c0 * 8);
        gl_lds16(Ab + off1 + k, Ad + c1 * 8);
        gl_lds16(Bb + off0 + k, Bd + c0 * 8);
        gl_lds16(Bb + off1 + k, Bd + c1 * 8);
    };

    // prologue: tiles 0 and 1 (8 loads in flight)
    stage(0, 0);
    stage(1, 1);

    for (int kt = 0; kt < T; ++kt) {
        if (kt + 1 < T) asm volatile("s_waitcnt vmcnt(4)" ::: "memory");
        else            asm volatile("s_waitcnt vmcnt(0)" ::: "memory");
        __builtin_amdgcn_s_barrier();           // BAR1: tile kt staged
        asm volatile("" ::: "memory");

        const unsigned short* aP = As0 + (kt & 1) * 4096 + aOff;
        const unsigned short* bP = Bs0 + (kt & 1) * 4096 + bOff;
        short8 af[4], bg[4];
#pragma unroll
        for (int i = 0; i < 4; ++i) af[i] = *(const short8*)(aP + i * 512);
#pragma unroll
        for (int j = 0; j < 4; ++j) bg[j] = *(const short8*)(bP + j * 512);
        __builtin_amdgcn_s_setprio(1);
#pragma unroll
        for (int i = 0; i < 4; ++i)
#pragma unroll
            for (int j = 0; j < 4; ++j)
                acc[i][j] = __builtin_amdgcn_mfma_f32_16x16x32_bf16(
                    af[i], bg[j], acc[i][j], 0, 0, 0);
        __builtin_amdgcn_s_setprio(0);
        asm volatile("" ::: "memory");
        __builtin_amdgcn_s_barrier();           // BAR2: reads of buf done
        if (kt + 2 < T) stage(kt + 2, kt & 1);  // overwrite consumed buffer
    }

    // C/D layout: col = lane&15, row = quad*4 + reg  [m89/m91 verified]
    unsigned short* CbW = Cb + (size_t)wr * N + wc;
#pragma unroll
    for (int i = 0; i < 4; ++i)
#pragma unroll
        for (int j = 0; j < 4; ++j)
#pragma unroll
            for (int r = 0; r < 4; ++r)
                CbW[(size_t)(i * 16 + quad * 4 + r) * N + j * 16 + l15] =
                    f2bf(acc[i][j][r]);

    if (Cm) {   // mirrored tile: r-values contiguous -> coalesced ushort4
        unsigned short* CmW = Cm + (size_t)wc * N + wr;
#pragma unroll
        for (int i = 0; i < 4; ++i)
#pragma unroll
            for (int j = 0; j < 4; ++j) {
                ushort4 o;
                o.x = f2bf(acc[i][j][0]);
                o.y = f2bf(acc[i][j][1]);
                o.z = f2bf(acc[i][j][2]);
                o.w = f2bf(acc[i][j][3]);
                *(ushort4*)(CmW + (size_t)(j * 16 + l15) * N + i * 16 + quad * 4) = o;
            }
    }
}

// ---------------------------------------------------------------------------
// Prep: [0,3072)   transpose+cvt x -> xT[b][d][l]
//       [3072,3216) transpose+cvt W -> WT[e][d]   (P's B-operand needs W^T)
//       [3216,...)  straight cvt main -> mainBF
// ---------------------------------------------------------------------------
__global__ __launch_bounds__(256) void prep_kernel(
    const float* __restrict__ x, unsigned short* __restrict__ xT,
    const float* __restrict__ W, unsigned short* __restrict__ WT,
    const float* __restrict__ mainp, unsigned short* __restrict__ mainBF) {
    const int bid = blockIdx.x;
    const int t   = threadIdx.x;
    if (bid < 3216) {
        __shared__ float tile[64][65];
        const float* src;
        unsigned short* dst;
        int ss, dstride;
        if (bid < 3072) {
            const int lb = bid & 15, rest = bid >> 4;
            const int db = rest % 12, b = rest / 12;
            src = x + ((size_t)b * kLX + lb * 64) * kD + db * 64;
            ss  = kD;
            dst = xT + ((size_t)b * kD + db * 64) * kLX + lb * 64;
            dstride = kLX;
        } else {
            const int ti = bid - 3072;
            const int d0 = (ti / 12) * 64, e0 = (ti % 12) * 64;
            src = W + (size_t)d0 * kD + e0;
            ss  = kD;
            dst = WT + (size_t)e0 * kD + d0;
            dstride = kD;
        }
        const int tx = t & 15, ty = t >> 4;
#pragma unroll
        for (int p = 0; p < 4; ++p) {
            int r = p * 16 + ty;
            float4 v = *(const float4*)(src + (size_t)r * ss + tx * 4);
            *(float4*)&tile[r][tx * 4] = v;
        }
        __syncthreads();
#pragma unroll
        for (int p = 0; p < 4; ++p) {
            int dr = p * 16 + ty;
            ushort4 o;
            o.x = f2bf(tile[tx * 4 + 0][dr]);
            o.y = f2bf(tile[tx * 4 + 1][dr]);
            o.z = f2bf(tile[tx * 4 + 2][dr]);
            o.w = f2bf(tile[tx * 4 + 3][dr]);
            *(ushort4*)(dst + (size_t)dr * dstride + tx * 4) = o;
        }
    } else {
        const long i = (long)(bid - 3216) * 256 + t;     // 8-elem chunk idx
        const long na8 = (long)kB * kLM * kD / 8;
        if (i >= na8) return;
        const float* s = mainp + i * 8;
        writeChunk(mainBF + i * 8, *(const float4*)s, *(const float4*)(s + 4));
    }
}

// ---------------------------------------------------------------------------
// Fused stage 2: [0,336)   G[b] = xT[b] @ xT[b]^T  (symmetric, triangle only,
//                           mirror-written; 21 tiles/batch)
//                [336,1104) P[b] = mainBF[b] @ W    (B-operand = WT, shared)
// Independent halves -> 1104 working blocks co-resident (vs 2 serial
// launches at 2.25-3 blocks/CU). Batch->XCD pinned in both halves.
// ---------------------------------------------------------------------------
__global__ __launch_bounds__(256) void gemm_stage2_kernel(
    const unsigned short* __restrict__ xT,
    const unsigned short* __restrict__ mainBF,
    const unsigned short* __restrict__ WT,
    unsigned short* __restrict__ G, unsigned short* __restrict__ P) {
    __shared__ unsigned short As[2][4096];
    __shared__ unsigned short Bs[2][4096];
    const int wgid = blockIdx.x;
    const unsigned short *Ab, *Bb;
    unsigned short *Cb, *Cm = nullptr;
    int K;
    if (wgid < 336) {
        const int xcd = wgid & 7, kk = wgid >> 3;       // kk in [0,42)
        const int grp = kk / 21, til = kk - grp * 21;
        const int b   = grp * 8 + xcd;
        int bi = (int)((sqrtf(8.f * (float)til + 1.f) - 1.f) * 0.5f);
        if (bi * (bi + 1) / 2 > til) --bi;
        else if ((bi + 1) * (bi + 2) / 2 <= til) ++bi;
        const int bj = til - bi * (bi + 1) / 2;         // bi >= bj
        K = kLX;
        const unsigned short* base = xT + (size_t)b * kD * kLX;
        Ab = base + (size_t)bi * 128 * kLX;
        Bb = base + (size_t)bj * 128 * kLX;
        unsigned short* Gb = G + (size_t)b * kD * kD;
        Cb = Gb + (size_t)bi * 128 * kD + bj * 128;
        if (bi != bj) Cm = Gb + (size_t)bj * 128 * kD + bi * 128;
    } else {
        const int pid = wgid - 336;
        const int xcd = pid & 7, kk = pid >> 3;         // kk in [0,96)
        const int grp = kk / 48, til = kk - grp * 48;
        const int b   = grp * 8 + xcd;
        const int bi  = til & 7, bj = til >> 3;         // 8 x 6 tiles
        K = kD;
        Ab = mainBF + (size_t)b * kLM * kD + (size_t)bi * 128 * kD;
        Bb = WT + (size_t)bj * 128 * kD;
        Cb = P + (size_t)b * kLM * kD + (size_t)bi * 128 * kD + bj * 128;
    }
    gemm_core(Ab, Bb, Cb, Cm, kD, K, &As[0][0], &Bs[0][0]);
}

// ---------------------------------------------------------------------------
// Stage 3: A[b] = P[b] @ G[b]   (G symmetric -> NT form with B = G directly)
// ---------------------------------------------------------------------------
__global__ __launch_bounds__(256) void gemm_a_kernel(
    const unsigned short* __restrict__ P, const unsigned short* __restrict__ G,
    unsigned short* __restrict__ Ao) {
    __shared__ unsigned short As[2][4096];
    __shared__ unsigned short Bs[2][4096];
    const int wgid = blockIdx.x;
    const int xcd = wgid & 7, kk = wgid >> 3;           // kk in [0,96)
    const int grp = kk / 48, til = kk - grp * 48;
    const int b   = grp * 8 + xcd;
    const int bi  = til & 7, bj = til >> 3;             // 8 x 6 tiles
    const unsigned short* Ab = P + (size_t)b * kLM * kD + (size_t)bi * 128 * kD;
    const unsigned short* Bb = G + (size_t)b * kD * kD + (size_t)bj * 128 * kD;
    unsigned short* Cb = Ao + (size_t)b * kLM * kD + (size_t)bi * 128 * kD + bj * 128;
    gemm_core(Ab, Bb, Cb, nullptr, kD, kD, &As[0][0], &Bs[0][0]);
}

// ---------------------------------------------------------------------------
// Fused beta + pooled. Grid (64,16). Wave handles 4 rows.
// Cross-wave LDS pre-reduction -> 1 atomicAdd per (s,lane) per block.
// ---------------------------------------------------------------------------
__global__ __launch_bounds__(256) void pool_kernel(
    const float* __restrict__ mainp, const unsigned short* __restrict__ Aout,
    const float* __restrict__ w, float* __restrict__ out) {
    __shared__ float red[4][24][64];   // 24 KB
    const int b     = blockIdx.y;
    const int chunk = blockIdx.x;           // 64 chunks of 16 rows
    const int t     = threadIdx.x;
    const int wave  = t >> 6, lane = t & 63;
    float w1[12], w2[12], ps[12], pm[12];
#pragma unroll
    for (int s = 0; s < 12; ++s) {
        w1[s] = w[s * 64 + lane];
        w2[s] = w[kD + s * 64 + lane];
        ps[s] = 0.f; pm[s] = 0.f;
    }
#pragma unroll
    for (int rr = 0; rr < 4; ++rr) {
        const int row = chunk * 16 + rr * 4 + wave;
        const float* mr = mainp + ((size_t)b * kLM + row) * kD;
        const unsigned short* ar = Aout + ((size_t)b * kLM + row) * kD;
        float sv[12], mv[12], acc = 0.f;
#pragma unroll
        for (int s = 0; s < 12; ++s) {
            float m_ = mr[s * 64 + lane];
            float a_ = bf2f(ar[s * 64 + lane]);
            sv[s] = m_ - a_;
            mv[s] = m_ * a_;
            acc += sv[s] * w1[s] + mv[s] * w2[s];
        }
#pragma unroll
        for (int off = 32; off; off >>= 1) acc += __shfl_xor(acc, off);
#pragma unroll
        for (int s = 0; s < 12; ++s) { ps[s] += acc * sv[s]; pm[s] += acc * mv[s]; }
    }
#pragma unroll
    for (int s = 0; s < 12; ++s) {
        red[wave][s][lane]      = ps[s];
        red[wave][12 + s][lane] = pm[s];
    }
    __syncthreads();
    float* ob = out + (size_t)b * 2 * kD;
    for (int v = t; v < 24 * 64; v += 256) {
        const int sl = v >> 6, ln = v & 63;
        const float sum = red[0][sl][ln] + red[1][sl][ln] +
                          red[2][sl][ln] + red[3][sl][ln];
        const int d = (sl < 12) ? sl * 64 + ln : kD + (sl - 12) * 64 + ln;
        atomicAdd(&ob[d], sum);
    }
}

extern "C" void kernel_launch(void* const* d_in, const int* in_sizes, int n_in,
                              void* d_out, int out_size, void* d_ws, size_t ws_size,
                              hipStream_t stream) {
    const float* mainp = (const float*)d_in[0];  // (B, LM, D)
    const float* x     = (const float*)d_in[1];  // (B, LX, D)
    const float* W     = (const float*)d_in[2];  // (D, D)
    const float* w     = (const float*)d_in[3];  // (2D, 1)
    float* out = (float*)d_out;                  // (B, 2D)

    char* p = (char*)d_ws;
    unsigned short* xT     = (unsigned short*)p; p += (size_t)kB * kD * kLX * 2;
    unsigned short* G      = (unsigned short*)p; p += (size_t)kB * kD * kD * 2;
    unsigned short* P      = (unsigned short*)p; p += (size_t)kB * kLM * kD * 2;
    unsigned short* Ao     = (unsigned short*)p; p += (size_t)kB * kLM * kD * 2;
    unsigned short* WT     = (unsigned short*)p; p += (size_t)kD * kD * 2;
    unsigned short* mainBF = (unsigned short*)p; p += (size_t)kB * kLM * kD * 2;

    hipMemsetAsync(out, 0, (size_t)kB * 2 * kD * sizeof(float), stream);

    // x -> xT (transposed bf16), W -> WT (transposed bf16), main -> bf16
    prep_kernel<<<dim3(3216 + kB * kLM * kD / 8 / 256), 256, 0, stream>>>(
        x, xT, W, WT, mainp, mainBF);

    // G = xT xT^T (triangle+mirror)  ||  P = main @ W   (independent, fused)
    gemm_stage2_kernel<<<dim3(336 + 768), 256, 0, stream>>>(xT, mainBF, WT, G, P);

    // A = P @ G  (G symmetric)
    gemm_a_kernel<<<dim3(768), 256, 0, stream>>>(P, G, Ao);

    pool_kernel<<<dim3(kLM / 16, kB), 256, 0, stream>>>(mainp, Ao, w, out);
}

// Round 3
// 216.229 us; speedup vs baseline: 1.0715x; 1.0715x over previous
//
#include <hip/hip_runtime.h>

constexpr int kB  = 16;
constexpr int kLM = 1024;
constexpr int kLX = 1024;
constexpr int kD  = 768;

using short8 = __attribute__((ext_vector_type(8))) short;
using f32x4  = __attribute__((ext_vector_type(4))) float;

__device__ __forceinline__ unsigned short f2bf(float f) {
    unsigned u = __float_as_uint(f);
    u = (u + 0x7FFF + ((u >> 16) & 1)) >> 16;   // RNE
    return (unsigned short)u;
}
__device__ __forceinline__ float bf2f(unsigned short h) {
    return __uint_as_float(((unsigned)h) << 16);
}

// async 16B global->LDS copy; dst must be wave-uniform base + lane*16.
__device__ __forceinline__ void gl_lds16(const unsigned short* g, unsigned short* l) {
    auto gp = (const __attribute__((address_space(1))) unsigned int*)g;
    auto lp = (__attribute__((address_space(3))) unsigned int*)l;
    __builtin_amdgcn_global_load_lds(gp, lp, 16, 0, 0);
}

// cvt 8 fp32 -> one 16B bf16 chunk
__device__ __forceinline__ void writeChunk(unsigned short* dst, float4 lo, float4 hi) {
    union { short8 v; unsigned short u[8]; } o;
    o.u[0] = f2bf(lo.x); o.u[1] = f2bf(lo.y); o.u[2] = f2bf(lo.z); o.u[3] = f2bf(lo.w);
    o.u[4] = f2bf(hi.x); o.u[5] = f2bf(hi.y); o.u[6] = f2bf(hi.z); o.u[7] = f2bf(hi.w);
    *(short8*)dst = o.v;
}

// ---------------------------------------------------------------------------
// Common 128x128 NT bf16 MFMA GEMM core. BK=64 (full 128B-line rows!), 256
// thr (2x2 waves), 4x4 MFMA frags x 2 k-slices = 32 MFMA/K-step/wave.
// C[i][j] = sum_k A[i,k] B[j,k].
//
// LDS tile layout (per operand, per buffer): 128 rows x 8 chunks of 16B,
// slot p holds global (row = p>>3, ch = (p&7) ^ (row&7))  [XOR swizzle].
//  - staging: thread t stages slots {t+256m}; per 8-lane group the global
//    addresses are one CONTIGUOUS 128B row segment (full cache line) ->
//    8 full lines per wave-load instruction, zero half-line waste.
//  - ds_read_b128: lane(q,r15) reads slot R*8 + ((s*4+q)^(R&7)) -> 2
//    lanes/bank = conflict-free (free 2-way).
// 2 LDS buffers (64 KB total -> 2 blocks/CU), depth-2 issue, counted
// vmcnt(8): tile t+1's 8 loads stay in flight across both barriers.
// Cm != nullptr: also write the mirrored (transposed) tile.
// ---------------------------------------------------------------------------
__device__ __forceinline__ void gemm_core(
    const unsigned short* __restrict__ Ab, const unsigned short* __restrict__ Bb,
    unsigned short* __restrict__ Cb, unsigned short* __restrict__ Cm,
    int N, int K, unsigned short* As0, unsigned short* Bs0) {
    const int t    = threadIdx.x;
    const int wave = t >> 6, lane = t & 63;
    const int wr = (wave >> 1) * 64, wc = (wave & 1) * 64;
    const int quad = lane >> 4, l15 = lane & 15;

    // staging: 4 chunks per operand per thread
    size_t goff[4];
    int    lof[4];
#pragma unroll
    for (int m = 0; m < 4; ++m) {
        const int p   = t + 256 * m;
        const int row = p >> 3;
        const int ch  = (p & 7) ^ (row & 7);
        goff[m] = (size_t)row * K + ch * 8;
        lof[m]  = p * 8;                       // LDS offset in shorts
    }

    // fragment read bases (shorts); k-slice 1 = base ^ 32 (perm ^ 4)
    const int perm0 = quad ^ (l15 & 7);
    const int aOff  = (wr + l15) * 64 + perm0 * 8;
    const int bOff  = (wc + l15) * 64 + perm0 * 8;

    f32x4 acc[4][4];
    const f32x4 z = {0.f, 0.f, 0.f, 0.f};
#pragma unroll
    for (int i = 0; i < 4; ++i)
#pragma unroll
        for (int j = 0; j < 4; ++j) acc[i][j] = z;

    const int T = K >> 6;

    auto stage = [&](int kt, int sel) {
        const size_t k = (size_t)kt << 6;
        unsigned short* Ad = As0 + sel * 8192;
        unsigned short* Bd = Bs0 + sel * 8192;
#pragma unroll
        for (int m = 0; m < 4; ++m) gl_lds16(Ab + goff[m] + k, Ad + lof[m]);
#pragma unroll
        for (int m = 0; m < 4; ++m) gl_lds16(Bb + goff[m] + k, Bd + lof[m]);
    };

    // prologue: tiles 0 and 1 (16 loads in flight)
    stage(0, 0);
    stage(1, 1);

    for (int kt = 0; kt < T; ++kt) {
        if (kt + 1 < T) asm volatile("s_waitcnt vmcnt(8)" ::: "memory");
        else            asm volatile("s_waitcnt vmcnt(0)" ::: "memory");
        __builtin_amdgcn_s_barrier();           // BAR1: tile kt staged
        asm volatile("" ::: "memory");

        const unsigned short* aP = As0 + (kt & 1) * 8192;
        const unsigned short* bP = Bs0 + (kt & 1) * 8192;
        short8 a0[4], b0[4], a1[4], b1[4];
#pragma unroll
        for (int i = 0; i < 4; ++i) a0[i] = *(const short8*)(aP + aOff + i * 1024);
#pragma unroll
        for (int j = 0; j < 4; ++j) b0[j] = *(const short8*)(bP + bOff + j * 1024);
        __builtin_amdgcn_s_setprio(1);
#pragma unroll
        for (int i = 0; i < 4; ++i)
#pragma unroll
            for (int j = 0; j < 4; ++j)
                acc[i][j] = __builtin_amdgcn_mfma_f32_16x16x32_bf16(
                    a0[i], b0[j], acc[i][j], 0, 0, 0);
        __builtin_amdgcn_s_setprio(0);
#pragma unroll
        for (int i = 0; i < 4; ++i) a1[i] = *(const short8*)(aP + (aOff ^ 32) + i * 1024);
#pragma unroll
        for (int j = 0; j < 4; ++j) b1[j] = *(const short8*)(bP + (bOff ^ 32) + j * 1024);
        __builtin_amdgcn_s_setprio(1);
#pragma unroll
        for (int i = 0; i < 4; ++i)
#pragma unroll
            for (int j = 0; j < 4; ++j)
                acc[i][j] = __builtin_amdgcn_mfma_f32_16x16x32_bf16(
                    a1[i], b1[j], acc[i][j], 0, 0, 0);
        __builtin_amdgcn_s_setprio(0);
        asm volatile("" ::: "memory");
        __builtin_amdgcn_s_barrier();           // BAR2: reads of buf done
        if (kt + 2 < T) stage(kt + 2, kt & 1);  // overwrite consumed buffer
    }

    // C/D layout: col = lane&15, row = quad*4 + reg  [m89/m91 verified]
    unsigned short* CbW = Cb + (size_t)wr * N + wc;
#pragma unroll
    for (int i = 0; i < 4; ++i)
#pragma unroll
        for (int j = 0; j < 4; ++j)
#pragma unroll
            for (int r = 0; r < 4; ++r)
                CbW[(size_t)(i * 16 + quad * 4 + r) * N + j * 16 + l15] =
                    f2bf(acc[i][j][r]);

    if (Cm) {   // mirrored tile: r-values contiguous -> coalesced ushort4
        unsigned short* CmW = Cm + (size_t)wc * N + wr;
#pragma unroll
        for (int i = 0; i < 4; ++i)
#pragma unroll
            for (int j = 0; j < 4; ++j) {
                ushort4 o;
                o.x = f2bf(acc[i][j][0]);
                o.y = f2bf(acc[i][j][1]);
                o.z = f2bf(acc[i][j][2]);
                o.w = f2bf(acc[i][j][3]);
                *(ushort4*)(CmW + (size_t)(j * 16 + l15) * N + i * 16 + quad * 4) = o;
            }
    }
}

// ---------------------------------------------------------------------------
// Prep: [0,3072)   transpose+cvt x -> xT[b][d][l]
//       [3072,3216) transpose+cvt W -> WT[e][d]
//       [3216,...)  straight cvt main -> mainBF
// ---------------------------------------------------------------------------
__global__ __launch_bounds__(256) void prep_kernel(
    const float* __restrict__ x, unsigned short* __restrict__ xT,
    const float* __restrict__ W, unsigned short* __restrict__ WT,
    const float* __restrict__ mainp, unsigned short* __restrict__ mainBF) {
    const int bid = blockIdx.x;
    const int t   = threadIdx.x;
    if (bid < 3216) {
        __shared__ float tile[64][65];
        const float* src;
        unsigned short* dst;
        int ss, dstride;
        if (bid < 3072) {
            const int lb = bid & 15, rest = bid >> 4;
            const int db = rest % 12, b = rest / 12;
            src = x + ((size_t)b * kLX + lb * 64) * kD + db * 64;
            ss  = kD;
            dst = xT + ((size_t)b * kD + db * 64) * kLX + lb * 64;
            dstride = kLX;
        } else {
            const int ti = bid - 3072;
            const int d0 = (ti / 12) * 64, e0 = (ti % 12) * 64;
            src = W + (size_t)d0 * kD + e0;
            ss  = kD;
            dst = WT + (size_t)e0 * kD + d0;
            dstride = kD;
        }
        const int tx = t & 15, ty = t >> 4;
#pragma unroll
        for (int p = 0; p < 4; ++p) {
            int r = p * 16 + ty;
            float4 v = *(const float4*)(src + (size_t)r * ss + tx * 4);
            *(float4*)&tile[r][tx * 4] = v;
        }
        __syncthreads();
#pragma unroll
        for (int p = 0; p < 4; ++p) {
            int dr = p * 16 + ty;
            ushort4 o;
            o.x = f2bf(tile[tx * 4 + 0][dr]);
            o.y = f2bf(tile[tx * 4 + 1][dr]);
            o.z = f2bf(tile[tx * 4 + 2][dr]);
            o.w = f2bf(tile[tx * 4 + 3][dr]);
            *(ushort4*)(dst + (size_t)dr * dstride + tx * 4) = o;
        }
    } else {
        const long i = (long)(bid - 3216) * 256 + t;     // 8-elem chunk idx
        const long na8 = (long)kB * kLM * kD / 8;
        if (i >= na8) return;
        const float* s = mainp + i * 8;
        writeChunk(mainBF + i * 8, *(const float4*)s, *(const float4*)(s + 4));
    }
}

// ---------------------------------------------------------------------------
// Fused stage 2: [0,336)   G[b] = xT[b] @ xT[b]^T  (symmetric, triangle only,
//                           mirror-written; 21 tiles/batch)
//                [336,1104) P[b] = mainBF[b] @ W    (B-operand = WT, shared)
// ---------------------------------------------------------------------------
__global__ __launch_bounds__(256) void gemm_stage2_kernel(
    const unsigned short* __restrict__ xT,
    const unsigned short* __restrict__ mainBF,
    const unsigned short* __restrict__ WT,
    unsigned short* __restrict__ G, unsigned short* __restrict__ P) {
    __shared__ unsigned short As[2][8192];
    __shared__ unsigned short Bs[2][8192];
    const int wgid = blockIdx.x;
    const unsigned short *Ab, *Bb;
    unsigned short *Cb, *Cm = nullptr;
    int K;
    if (wgid < 336) {
        const int xcd = wgid & 7, kk = wgid >> 3;       // kk in [0,42)
        const int grp = kk / 21, til = kk - grp * 21;
        const int b   = grp * 8 + xcd;
        int bi = (int)((sqrtf(8.f * (float)til + 1.f) - 1.f) * 0.5f);
        if (bi * (bi + 1) / 2 > til) --bi;
        else if ((bi + 1) * (bi + 2) / 2 <= til) ++bi;
        const int bj = til - bi * (bi + 1) / 2;         // bi >= bj
        K = kLX;
        const unsigned short* base = xT + (size_t)b * kD * kLX;
        Ab = base + (size_t)bi * 128 * kLX;
        Bb = base + (size_t)bj * 128 * kLX;
        unsigned short* Gb = G + (size_t)b * kD * kD;
        Cb = Gb + (size_t)bi * 128 * kD + bj * 128;
        if (bi != bj) Cm = Gb + (size_t)bj * 128 * kD + bi * 128;
    } else {
        const int pid = wgid - 336;
        const int xcd = pid & 7, kk = pid >> 3;         // kk in [0,96)
        const int grp = kk / 48, til = kk - grp * 48;
        const int b   = grp * 8 + xcd;
        const int bi  = til & 7, bj = til >> 3;         // 8 x 6 tiles
        K = kD;
        Ab = mainBF + (size_t)b * kLM * kD + (size_t)bi * 128 * kD;
        Bb = WT + (size_t)bj * 128 * kD;
        Cb = P + (size_t)b * kLM * kD + (size_t)bi * 128 * kD + bj * 128;
    }
    gemm_core(Ab, Bb, Cb, Cm, kD, K, &As[0][0], &Bs[0][0]);
}

// ---------------------------------------------------------------------------
// Stage 3: A[b] = P[b] @ G[b]   (G symmetric -> NT form with B = G directly)
// ---------------------------------------------------------------------------
__global__ __launch_bounds__(256) void gemm_a_kernel(
    const unsigned short* __restrict__ P, const unsigned short* __restrict__ G,
    unsigned short* __restrict__ Ao) {
    __shared__ unsigned short As[2][8192];
    __shared__ unsigned short Bs[2][8192];
    const int wgid = blockIdx.x;
    const int xcd = wgid & 7, kk = wgid >> 3;           // kk in [0,96)
    const int grp = kk / 48, til = kk - grp * 48;
    const int b   = grp * 8 + xcd;
    const int bi  = til & 7, bj = til >> 3;             // 8 x 6 tiles
    const unsigned short* Ab = P + (size_t)b * kLM * kD + (size_t)bi * 128 * kD;
    const unsigned short* Bb = G + (size_t)b * kD * kD + (size_t)bj * 128 * kD;
    unsigned short* Cb = Ao + (size_t)b * kLM * kD + (size_t)bi * 128 * kD + bj * 128;
    gemm_core(Ab, Bb, Cb, nullptr, kD, kD, &As[0][0], &Bs[0][0]);
}

// ---------------------------------------------------------------------------
// Fused beta + pooled. Grid (64,16). Wave handles 4 rows.
// Cross-wave LDS pre-reduction -> 1 atomicAdd per (s,lane) per block.
// ---------------------------------------------------------------------------
__global__ __launch_bounds__(256) void pool_kernel(
    const float* __restrict__ mainp, const unsigned short* __restrict__ Aout,
    const float* __restrict__ w, float* __restrict__ out) {
    __shared__ float red[4][24][64];   // 24 KB
    const int b     = blockIdx.y;
    const int chunk = blockIdx.x;           // 64 chunks of 16 rows
    const int t     = threadIdx.x;
    const int wave  = t >> 6, lane = t & 63;
    float w1[12], w2[12], ps[12], pm[12];
#pragma unroll
    for (int s = 0; s < 12; ++s) {
        w1[s] = w[s * 64 + lane];
        w2[s] = w[kD + s * 64 + lane];
        ps[s] = 0.f; pm[s] = 0.f;
    }
#pragma unroll
    for (int rr = 0; rr < 4; ++rr) {
        const int row = chunk * 16 + rr * 4 + wave;
        const float* mr = mainp + ((size_t)b * kLM + row) * kD;
        const unsigned short* ar = Aout + ((size_t)b * kLM + row) * kD;
        float sv[12], mv[12], acc = 0.f;
#pragma unroll
        for (int s = 0; s < 12; ++s) {
            float m_ = mr[s * 64 + lane];
            float a_ = bf2f(ar[s * 64 + lane]);
            sv[s] = m_ - a_;
            mv[s] = m_ * a_;
            acc += sv[s] * w1[s] + mv[s] * w2[s];
        }
#pragma unroll
        for (int off = 32; off; off >>= 1) acc += __shfl_xor(acc, off);
#pragma unroll
        for (int s = 0; s < 12; ++s) { ps[s] += acc * sv[s]; pm[s] += acc * mv[s]; }
    }
#pragma unroll
    for (int s = 0; s < 12; ++s) {
        red[wave][s][lane]      = ps[s];
        red[wave][12 + s][lane] = pm[s];
    }
    __syncthreads();
    float* ob = out + (size_t)b * 2 * kD;
    for (int v = t; v < 24 * 64; v += 256) {
        const int sl = v >> 6, ln = v & 63;
        const float sum = red[0][sl][ln] + red[1][sl][ln] +
                          red[2][sl][ln] + red[3][sl][ln];
        const int d = (sl < 12) ? sl * 64 + ln : kD + (sl - 12) * 64 + ln;
        atomicAdd(&ob[d], sum);
    }
}

extern "C" void kernel_launch(void* const* d_in, const int* in_sizes, int n_in,
                              void* d_out, int out_size, void* d_ws, size_t ws_size,
                              hipStream_t stream) {
    const float* mainp = (const float*)d_in[0];  // (B, LM, D)
    const float* x     = (const float*)d_in[1];  // (B, LX, D)
    const float* W     = (const float*)d_in[2];  // (D, D)
    const float* w     = (const float*)d_in[3];  // (2D, 1)
    float* out = (float*)d_out;                  // (B, 2D)

    char* p = (char*)d_ws;
    unsigned short* xT     = (unsigned short*)p; p += (size_t)kB * kD * kLX * 2;
    unsigned short* G      = (unsigned short*)p; p += (size_t)kB * kD * kD * 2;
    unsigned short* P      = (unsigned short*)p; p += (size_t)kB * kLM * kD * 2;
    unsigned short* Ao     = (unsigned short*)p; p += (size_t)kB * kLM * kD * 2;
    unsigned short* WT     = (unsigned short*)p; p += (size_t)kD * kD * 2;
    unsigned short* mainBF = (unsigned short*)p; p += (size_t)kB * kLM * kD * 2;

    hipMemsetAsync(out, 0, (size_t)kB * 2 * kD * sizeof(float), stream);

    // x -> xT (transposed bf16), W -> WT (transposed bf16), main -> bf16
    prep_kernel<<<dim3(3216 + kB * kLM * kD / 8 / 256), 256, 0, stream>>>(
        x, xT, W, WT, mainp, mainBF);

    // G = xT xT^T (triangle+mirror)  ||  P = main @ W   (independent, fused)
    gemm_stage2_kernel<<<dim3(336 + 768), 256, 0, stream>>>(xT, mainBF, WT, G, P);

    // A = P @ G  (G symmetric)
    gemm_a_kernel<<<dim3(768), 256, 0, stream>>>(P, G, Ao);

    pool_kernel<<<dim3(kLM / 16, kB), 256, 0, stream>>>(mainp, Ao, w, out);
}